// Round 2
// baseline (429.778 us; speedup 1.0000x reference)
//
#include <hip/hip_runtime.h>
#include <math.h>

#define HIDDEN 512
#define BATCH  16
#define NN     2048

// Kernel 1: d[b,n] = 1/sqrt( sum_k relu(adj[b,n,k]) + 1 )
// One wave per row (2048 floats = 8 float4/lane), 4 rows per 256-thread block.
// No LDS, no barrier — pure shuffle reduction.
__global__ __launch_bounds__(256) void k_rowsum(const float* __restrict__ adj,
                                                float* __restrict__ d) {
    const int row  = (blockIdx.x << 2) + (threadIdx.x >> 6);   // 0 .. B*N-1
    const int lane = threadIdx.x & 63;
    const float4* a4 = (const float4*)(adj + (size_t)row * NN);
    float s = 0.0f;
    #pragma unroll
    for (int j = 0; j < 8; ++j) {
        float4 v = a4[lane + 64 * j];
        s += fmaxf(v.x, 0.f) + fmaxf(v.y, 0.f) + fmaxf(v.z, 0.f) + fmaxf(v.w, 0.f);
    }
    #pragma unroll
    for (int off = 32; off > 0; off >>= 1) s += __shfl_down(s, off);
    if (lane == 0) d[row] = 1.0f / sqrtf(s + 1.0f);            // +1 from identity diag
}

// Kernel 2 (fused w0+y): y[b,h] = d[b,0] * sum_m (relu(adj[b,0,m]) + (m==0)) * d[b,m] * feat[b,h,m]
// One wave per (b,h) row. adj row 0 (8 KB/batch) and d (128 KB) stay L2-hot
// across the 8192 rows, so recomputing w0 inline costs only L2 reads + a few VALU.
__global__ __launch_bounds__(256) void k_yw(const float* __restrict__ feat,
                                            const float* __restrict__ adj,
                                            const float* __restrict__ dvec,
                                            float* __restrict__ y) {
    const int row  = (blockIdx.x << 2) + (threadIdx.x >> 6);   // 0 .. B*H-1
    const int lane = threadIdx.x & 63;
    const int b = row >> 9;                                    // / HIDDEN
    const float4* f4 = (const float4*)(feat + (size_t)row * NN);
    const float4* a4 = (const float4*)(adj + (size_t)b * NN * NN);  // row 0 of batch b
    const float4* d4 = (const float4*)(dvec + b * NN);
    float s = 0.0f;
    #pragma unroll
    for (int j = 0; j < 8; ++j) {
        const int idx = lane + 64 * j;
        float4 f = f4[idx];
        float4 a = a4[idx];
        float4 dd = d4[idx];
        float wx = fmaxf(a.x, 0.f) + (idx == 0 ? 1.0f : 0.0f); // identity hits only m==0
        s += wx             * dd.x * f.x;
        s += fmaxf(a.y, 0.f) * dd.y * f.y;
        s += fmaxf(a.z, 0.f) * dd.z * f.z;
        s += fmaxf(a.w, 0.f) * dd.w * f.w;
    }
    #pragma unroll
    for (int off = 32; off > 0; off >>= 1) s += __shfl_down(s, off);
    if (lane == 0) y[row] = dvec[b * NN] * s;                  // d[b,0] uniform scale
}

// Kernel 3: out[b,k] = tanh( bias[b,k] + sum_h y[b,h] * W[h,k] )
// One thread per (b,k); b is block-uniform so y loads scalarize; W coalesced over k.
__global__ __launch_bounds__(256) void k_out(const float* __restrict__ W,
                                             const float* __restrict__ bias,
                                             const float* __restrict__ y,
                                             float* __restrict__ out) {
    const int i = blockIdx.x * 256 + threadIdx.x;              // 0 .. B*H-1
    const int b = i >> 9;
    const int k = i & (HIDDEN - 1);
    const float* yb = y + b * HIDDEN;
    float s = bias[i];
    #pragma unroll 8
    for (int h = 0; h < HIDDEN; ++h) s += yb[h] * W[h * HIDDEN + k];
    out[i] = tanhf(s);
}

extern "C" void kernel_launch(void* const* d_in, const int* in_sizes, int n_in,
                              void* d_out, int out_size, void* d_ws, size_t ws_size,
                              hipStream_t stream) {
    const float* feat = (const float*)d_in[0];   // [B, H, N]
    const float* adj  = (const float*)d_in[1];   // [B, N, N]
    const float* W    = (const float*)d_in[2];   // [H, H]
    const float* bias = (const float*)d_in[3];   // [B, H]
    float* out = (float*)d_out;                  // [B, H]

    float* d = (float*)d_ws;                     // B*N
    float* y = d + BATCH * NN;                   // B*H

    k_rowsum<<<(BATCH * NN) / 4, 256, 0, stream>>>(adj, d);
    k_yw<<<(BATCH * HIDDEN) / 4, 256, 0, stream>>>(feat, adj, d, y);
    k_out<<<(BATCH * HIDDEN) / 256, 256, 0, stream>>>(W, bias, y, out);
}